// Round 14
// baseline (305.322 us; speedup 1.0000x reference)
//
#include <hip/hip_runtime.h>
#include <hip/hip_bf16.h>
#include <stdint.h>

// SelfAttention: x(4,2048,1024) f32; W_qkv(3072,1024); W_out(1024,1024); b_out(1024)
// out = OutProj(Attn(QKV(x)))  f32 (4,2048,1024)
// Strategy: fp16 MFMA everywhere (threshold 5.5e-3; measured absmax ~2e-3).
// R14: attn = R10 (best: 115.4us) minus the vestigial max machinery.
//      Softmax uses m==0 fixed: P = exp2(s) directly. Scores s = qk*0.125*log2e
//      are ~N(0,1.44^2), max ~5 over 2048 keys -> exp2 <= ~64, fp16/f32 safe;
//      the defer-max rescale never fired in 13 rounds (absmax bit-stable).
//      Removes ~100 VALU inst/kt (max3 tree, 2 shfl, __any, rescale path).
//      R13's double-buffer reverted (VGPR 116 -> occupancy loss, 3rd failure).

typedef _Float16 half8 __attribute__((ext_vector_type(8)));
typedef _Float16 half4 __attribute__((ext_vector_type(4)));
typedef __fp16 fp16x2 __attribute__((ext_vector_type(2)));  // native cvt_pkrtz type
typedef float floatx4 __attribute__((ext_vector_type(4)));

#define E 1024
#define NH 16
#define DH 64
#define SEQ 2048
#define BATCH 4

__device__ __forceinline__ void gload_lds16(const void* g, void* lds) {
  typedef __attribute__((address_space(1))) void gv;
  typedef __attribute__((address_space(3))) void lv;
  __builtin_amdgcn_global_load_lds((gv*)g, (lv*)lds, 16, 0, 0);
}

__device__ __forceinline__ float fast_exp2(float x) {
#if __has_builtin(__builtin_amdgcn_exp2f)
  return __builtin_amdgcn_exp2f(x);
#else
  return exp2f(x);
#endif
}

// ---------------------------------------------------------------- convert (fused x, Wqkv, Wout)
__global__ __launch_bounds__(256)
void cvt3_f32_f16(const float* __restrict__ a, _Float16* __restrict__ oa, int na,
                  const float* __restrict__ b, _Float16* __restrict__ ob, int nb,
                  const float* __restrict__ c, _Float16* __restrict__ oc, int nc) {
  int i = blockIdx.x * 256 + threadIdx.x;
  const float* in;
  _Float16* out;
  int idx;
  if (i < na) { in = a; out = oa; idx = i; }
  else if (i < na + nb) { in = b; out = ob; idx = i - na; }
  else if (i < na + nb + nc) { in = c; out = oc; idx = i - na - nb; }
  else return;
  const float4* p = (const float4*)in;
  float4 u = p[2 * idx], v = p[2 * idx + 1];
  half8 h;
  h[0] = (_Float16)u.x; h[1] = (_Float16)u.y; h[2] = (_Float16)u.z; h[3] = (_Float16)u.w;
  h[4] = (_Float16)v.x; h[5] = (_Float16)v.y; h[6] = (_Float16)v.z; h[7] = (_Float16)v.w;
  ((half8*)out)[idx] = h;
}

// ---------------------------------------------------------------- QKV GEMM
// C[8192,3072] = A[8192,1024] * W[3072,1024]^T ; scatter into q/k (b,h,tok,d) and
// V^T (b,h,d,tok) fp16. Q pre-scaled by 1/sqrt(Dh)*log2(e) for exp2 softmax.
__global__ __launch_bounds__(256)
void gemm_qkv(const _Float16* __restrict__ A, const _Float16* __restrict__ W,
              _Float16* __restrict__ qo, _Float16* __restrict__ ko, _Float16* __restrict__ vt) {
  __shared__ __align__(16) _Float16 As[128 * 64];
  __shared__ __align__(16) _Float16 Bs[128 * 64];
  const int t = threadIdx.x;
  const int w = t >> 6, l = t & 63;
  const int wr = w >> 1, wc = w & 1;
  const int lr = l & 15, hi = l >> 4;
  const int tileRow = blockIdx.y * 128;
  const int tileCol = blockIdx.x * 128;
  const int ldsW = (t & ~63) * 16;
  floatx4 acc[4][4] = {};

  for (int k0 = 0; k0 < 1024; k0 += 64) {
    __syncthreads();
#pragma unroll
    for (int c = 0; c < 4; ++c) {
      int idx = c * 256 + t;
      int row = idx >> 3, g = idx & 7;
      gload_lds16(A + (size_t)(tileRow + row) * 1024 + k0 + g * 8, (char*)As + c * 4096 + ldsW);
      gload_lds16(W + (size_t)(tileCol + row) * 1024 + k0 + g * 8, (char*)Bs + c * 4096 + ldsW);
    }
    __syncthreads();
#pragma unroll
    for (int kk = 0; kk < 2; ++kk) {
      half8 af[4], bf[4];
#pragma unroll
      for (int m = 0; m < 4; ++m)
        af[m] = *(const half8*)(As + (wr * 64 + m * 16 + lr) * 64 + kk * 32 + hi * 8);
#pragma unroll
      for (int n = 0; n < 4; ++n)
        bf[n] = *(const half8*)(Bs + (wc * 64 + n * 16 + lr) * 64 + kk * 32 + hi * 8);
#pragma unroll
      for (int m = 0; m < 4; ++m)
#pragma unroll
        for (int n = 0; n < 4; ++n)
          acc[m][n] = __builtin_amdgcn_mfma_f32_16x16x32_f16(af[m], bf[n], acc[m][n], 0, 0, 0);
    }
  }
  // epilogue: C/D layout col=lane&15, row=(lane>>4)*4+j  [m89]
  const int sec = tileCol >> 10;  // 128-tile never straddles a 1024 section
  const int b = tileRow >> 11;
  const int tokBase = (tileRow & 2047) + wr * 64;
  if (sec == 2) {
    // V^T: vt[((b*NH+h)*DH + d)*SEQ + tok]; 4 consecutive tok per lane -> 8B stores
#pragma unroll
    for (int n = 0; n < 4; ++n) {
      int col = (tileCol & 1023) + wc * 64 + n * 16 + lr;
      int h = col >> 6, d = col & 63;
      _Float16* base = vt + (((size_t)b * NH + h) * DH + d) * SEQ + tokBase;
#pragma unroll
      for (int m = 0; m < 4; ++m) {
        half4 v;
#pragma unroll
        for (int j = 0; j < 4; ++j) v[j] = (_Float16)acc[m][n][j];
        *(half4*)(base + m * 16 + hi * 4) = v;
      }
    }
  } else {
    _Float16* dst = sec == 0 ? qo : ko;
    const float scaleq = sec == 0 ? 0.18033688011112042f : 1.0f;  // 0.125 * log2(e)
#pragma unroll
    for (int n = 0; n < 4; ++n) {
      int col = (tileCol & 1023) + wc * 64 + n * 16 + lr;
      int h = col >> 6, d = col & 63;
      _Float16* base = dst + (((size_t)b * NH + h) * SEQ + tokBase) * DH + d;
#pragma unroll
      for (int m = 0; m < 4; ++m)
#pragma unroll
        for (int j = 0; j < 4; ++j)
          base[(size_t)(m * 16 + hi * 4 + j) * DH] = (_Float16)(acc[m][n][j] * scaleq);
    }
  }
}

// ---------------------------------------------------------------- flash attention
// grid(1024 linear); XCD-chunked swizzle (FETCH 139->25MB measured).
// 4 waves x 32 q-rows (2 groups of 16); KV tile 128 = 2 sequential 64-key
// subtiles per barrier pair. global_load_lds staging.
// Swapped QK^T; softmax with m==0 fixed (no max tracking; see header note);
// per-lane l partials reduced in epilogue.
__global__ __launch_bounds__(256, 3)
void attn(const _Float16* __restrict__ Q, const _Float16* __restrict__ Kg,
          const _Float16* __restrict__ VT, _Float16* __restrict__ O) {
  __shared__ __align__(16) _Float16 Ks[2][64 * 64];  // [sub][key][d] swizzled
  __shared__ __align__(16) _Float16 Vs[2][64 * 64];  // [sub][d][key] swizzled
  __shared__ __align__(16) _Float16 Ps[4][16 * 64];  // per-wave P [q][key], reused per group
  const int orig = blockIdx.x;
  const int nid = (orig & 7) * 128 + (orig >> 3);  // bijective: 1024 = 8 * 128
  const int qt = nid & 15, bh = nid >> 4;
  const int t = threadIdx.x, w = t >> 6, l = t & 63;
  const int lr = l & 15, hi = l >> 4;
  const int ldsW = (t & ~63) * 16;
  const _Float16* qb = Q + ((size_t)bh * SEQ + qt * 128 + w * 32) * DH;
  half8 qf[2][2];
#pragma unroll
  for (int g = 0; g < 2; ++g) {
    qf[g][0] = *(const half8*)(qb + (g * 16 + lr) * DH + hi * 8);
    qf[g][1] = *(const half8*)(qb + (g * 16 + lr) * DH + 32 + hi * 8);
  }
  floatx4 o0[4] = {}, o1[4] = {};
  float l0 = 0.f, l1 = 0.f;  // per-lane partial sums; reduced in epilogue
  const _Float16* kb = Kg + (size_t)bh * SEQ * DH;
  const _Float16* vb = VT + (size_t)bh * DH * SEQ;
  char* pw = (char*)&Ps[w][0];
  const int lrm = lr & 7;
  uint32_t wra[4], rda[2];
#pragma unroll
  for (int n = 0; n < 4; ++n)
    wra[n] = lr * 128 + ((((2 * n + (hi >> 1)) ^ lrm)) << 4) + (hi & 1) * 8;
#pragma unroll
  for (int kk = 0; kk < 2; ++kk)
    rda[kk] = lr * 128 + (((4 * kk + hi) ^ lrm) << 4);

  // softmax slice (m==0): P = exp2(s) directly, accumulate per-lane row-sum
  auto sm = [&](floatx4(&s)[4], float& lsum, fp16x2(&pk)[4][2]) {
    float rs = 0.f;
#pragma unroll
    for (int n = 0; n < 4; ++n) {
      float p0 = fast_exp2(s[n][0]), p1 = fast_exp2(s[n][1]);
      float p2 = fast_exp2(s[n][2]), p3 = fast_exp2(s[n][3]);
      pk[n][0] = __builtin_amdgcn_cvt_pkrtz(p0, p1);
      pk[n][1] = __builtin_amdgcn_cvt_pkrtz(p2, p3);
      rs += (p0 + p1) + (p2 + p3);
    }
    lsum += rs;
  };

  // P round-trip through per-wave LDS; emits the two A-frags for PV
  auto proute = [&](fp16x2(&pk)[4][2], half8(&pf)[2]) {
#pragma unroll
    for (int n = 0; n < 4; ++n) {
      uint2 v;
      v.x = __builtin_bit_cast(uint32_t, pk[n][0]);
      v.y = __builtin_bit_cast(uint32_t, pk[n][1]);
      *(uint2*)(pw + wra[n]) = v;
    }
    pf[0] = *(const half8*)(pw + rda[0]);
    pf[1] = *(const half8*)(pw + rda[1]);
  };

  for (int kt = 0; kt < SEQ / 128; ++kt) {
    __syncthreads();
    // stage 128 keys: K rows 0..127 -> Ks[0..1]; V (sub, d) -> Vs[0..1]
#pragma unroll
    for (int c = 0; c < 4; ++c) {
      int idx = c * 256 + t;
      int row = idx >> 3, g = idx & 7, gs = g ^ (row & 7);
      gload_lds16(kb + (size_t)(kt * 128 + row) * DH + gs * 8, (char*)Ks + c * 4096 + ldsW);
      int d = row & 63, sv = row >> 6;
      gload_lds16(vb + (size_t)d * SEQ + kt * 128 + sv * 64 + gs * 8,
                  (char*)Vs + c * 4096 + ldsW);
    }
    __syncthreads();
#pragma unroll
    for (int sb = 0; sb < 2; ++sb) {
      const char* Kbase = (const char*)Ks + sb * 8192;
      const char* Vbase = (const char*)Vs + sb * 8192;
      // K frags once, used by both q-groups
      half8 af[8];
#pragma unroll
      for (int kk = 0; kk < 2; ++kk) {
        int gl = kk * 4 + hi;
#pragma unroll
        for (int n = 0; n < 4; ++n) {
          int key = n * 16 + lr;
          af[kk * 4 + n] = *(const half8*)(Kbase + key * 128 + ((gl ^ (key & 7)) << 4));
        }
      }
      // --- group 0 QK^T (C = 0; scores used raw)
      floatx4 s0[4] = {};
      __builtin_amdgcn_s_setprio(1);
#pragma unroll
      for (int kk = 0; kk < 2; ++kk)
#pragma unroll
        for (int n = 0; n < 4; ++n)
          s0[n] = __builtin_amdgcn_mfma_f32_16x16x32_f16(af[kk * 4 + n], qf[0][kk], s0[n], 0, 0, 0);
      __builtin_amdgcn_s_setprio(0);
      // group 0 softmax + P route (s0 dies here)
      fp16x2 pk[4][2];
      half8 pf[2];
      sm(s0, l0, pk);
      proute(pk, pf);
      // --- group 1 QK^T (last use of af)
      floatx4 s1[4] = {};
      __builtin_amdgcn_s_setprio(1);
#pragma unroll
      for (int kk = 0; kk < 2; ++kk)
#pragma unroll
        for (int n = 0; n < 4; ++n)
          s1[n] = __builtin_amdgcn_mfma_f32_16x16x32_f16(af[kk * 4 + n], qf[1][kk], s1[n], 0, 0, 0);
      __builtin_amdgcn_s_setprio(0);
      // V frags once, used by both q-groups
      half8 vf[8];
#pragma unroll
      for (int kk = 0; kk < 2; ++kk) {
        int gl = kk * 4 + hi;
#pragma unroll
        for (int n = 0; n < 4; ++n) {
          int d = n * 16 + lr;
          vf[kk * 4 + n] = *(const half8*)(Vbase + d * 128 + ((gl ^ (d & 7)) << 4));
        }
      }
      // --- PV group 0
      __builtin_amdgcn_s_setprio(1);
#pragma unroll
      for (int kk = 0; kk < 2; ++kk)
#pragma unroll
        for (int n = 0; n < 4; ++n)
          o0[n] = __builtin_amdgcn_mfma_f32_16x16x32_f16(pf[kk], vf[kk * 4 + n], o0[n], 0, 0, 0);
      __builtin_amdgcn_s_setprio(0);
      // group 1 softmax + P route (Ps reused; same-wave DS ordering keeps it safe)
      sm(s1, l1, pk);
      proute(pk, pf);
      // --- PV group 1
      __builtin_amdgcn_s_setprio(1);
#pragma unroll
      for (int kk = 0; kk < 2; ++kk)
#pragma unroll
        for (int n = 0; n < 4; ++n)
          o1[n] = __builtin_amdgcn_mfma_f32_16x16x32_f16(pf[kk], vf[kk * 4 + n], o1[n], 0, 0, 0);
      __builtin_amdgcn_s_setprio(0);
    }
  }
  // epilogue: reduce l partials (4 lanes per q-row), normalize + store both groups
  l0 += __shfl_xor(l0, 16); l0 += __shfl_xor(l0, 32);
  l1 += __shfl_xor(l1, 16); l1 += __shfl_xor(l1, 32);
  const int b = bh >> 4, h = bh & 15;
#pragma unroll
  for (int g = 0; g < 2; ++g) {
    const floatx4* oa = g == 0 ? o0 : o1;
    float lg = g == 0 ? l0 : l1;
#pragma unroll
    for (int j = 0; j < 4; ++j) {
      float lj = __shfl(lg, hi * 4 + j);
      float inv = 1.f / lj;
      int tok = qt * 128 + w * 32 + g * 16 + hi * 4 + j;
      _Float16* ob = O + ((size_t)b * SEQ + tok) * E + h * DH;
#pragma unroll
      for (int n = 0; n < 4; ++n) ob[n * 16 + lr] = (_Float16)(oa[n][j] * inv);
    }
  }
}

// ---------------------------------------------------------------- out projection
__global__ __launch_bounds__(256)
void gemm_out(const _Float16* __restrict__ A, const _Float16* __restrict__ W,
              const float* __restrict__ bias, float* __restrict__ out) {
  __shared__ __align__(16) _Float16 As[128 * 64];
  __shared__ __align__(16) _Float16 Bs[128 * 64];
  const int t = threadIdx.x;
  const int w = t >> 6, l = t & 63;
  const int wr = w >> 1, wc = w & 1;
  const int lr = l & 15, hi = l >> 4;
  const int tileRow = blockIdx.y * 128;
  const int tileCol = blockIdx.x * 128;
  const int ldsW = (t & ~63) * 16;
  floatx4 acc[4][4] = {};

  for (int k0 = 0; k0 < 1024; k0 += 64) {
    __syncthreads();
#pragma unroll
    for (int c = 0; c < 4; ++c) {
      int idx = c * 256 + t;
      int row = idx >> 3, g = idx & 7;
      gload_lds16(A + (size_t)(tileRow + row) * 1024 + k0 + g * 8, (char*)As + c * 4096 + ldsW);
      gload_lds16(W + (size_t)(tileCol + row) * 1024 + k0 + g * 8, (char*)Bs + c * 4096 + ldsW);
    }
    __syncthreads();
#pragma unroll
    for (int kk = 0; kk < 2; ++kk) {
      half8 af[4], bf[4];
#pragma unroll
      for (int m = 0; m < 4; ++m)
        af[m] = *(const half8*)(As + (wr * 64 + m * 16 + lr) * 64 + kk * 32 + hi * 8);
#pragma unroll
      for (int n = 0; n < 4; ++n)
        bf[n] = *(const half8*)(Bs + (wc * 64 + n * 16 + lr) * 64 + kk * 32 + hi * 8);
#pragma unroll
      for (int m = 0; m < 4; ++m)
#pragma unroll
        for (int n = 0; n < 4; ++n)
          acc[m][n] = __builtin_amdgcn_mfma_f32_16x16x32_f16(af[m], bf[n], acc[m][n], 0, 0, 0);
    }
  }
#pragma unroll
  for (int n = 0; n < 4; ++n) {
    int col = tileCol + wc * 64 + n * 16 + lr;
    float bv = bias[col];
#pragma unroll
    for (int m = 0; m < 4; ++m) {
      int row = tileRow + wr * 64 + m * 16 + hi * 4;
#pragma unroll
      for (int j = 0; j < 4; ++j)
        out[(size_t)(row + j) * E + col] = acc[m][n][j] + bv;
    }
  }
}

// ---------------------------------------------------------------- launch
extern "C" void kernel_launch(void* const* d_in, const int* in_sizes, int n_in,
                              void* d_out, int out_size, void* d_ws, size_t ws_size,
                              hipStream_t stream) {
  const float* x = (const float*)d_in[0];
  const float* Wqkv = (const float*)d_in[1];
  const float* Wout = (const float*)d_in[2];
  const float* bout = (const float*)d_in[3];
  float* out = (float*)d_out;
  char* ws = (char*)d_ws;
  // workspace: [0,16M) x16 (later ao16) | [16,32) q16 | [32,48) k16 |
  //            [48,64) vt16 (V^T, written by gemm_qkv) | [64,70) wq16 | [70,72) wo16
  _Float16* x16 = (_Float16*)(ws);
  _Float16* q16 = (_Float16*)(ws + (16u << 20));
  _Float16* k16 = (_Float16*)(ws + (32u << 20));
  _Float16* vt16 = (_Float16*)(ws + (48u << 20));
  _Float16* wq16 = (_Float16*)(ws + (64u << 20));
  _Float16* wo16 = (_Float16*)(ws + (70u << 20));
  _Float16* ao16 = x16;  // x dead after gemm_qkv

  int n8x = in_sizes[0] / 8, n8q = in_sizes[1] / 8, n8o = in_sizes[2] / 8;
  int n8 = n8x + n8q + n8o;
  cvt3_f32_f16<<<(n8 + 255) / 256, 256, 0, stream>>>(x, x16, n8x, Wqkv, wq16, n8q, Wout, wo16, n8o);
  gemm_qkv<<<dim3(24, 64), 256, 0, stream>>>(x16, wq16, q16, k16, vt16);
  attn<<<dim3(1024), 256, 0, stream>>>(q16, k16, vt16, ao16);
  gemm_out<<<dim3(8, 64), 256, 0, stream>>>(ao16, wo16, bout, out);
}

// Round 15
// 221.155 us; speedup vs baseline: 1.3806x; 1.3806x over previous
//
#include <hip/hip_runtime.h>
#include <hip/hip_bf16.h>
#include <stdint.h>

// SelfAttention: x(4,2048,1024) f32; W_qkv(3072,1024); W_out(1024,1024); b_out(1024)
// out = OutProj(Attn(QKV(x)))  f32 (4,2048,1024)
// Strategy: fp16 MFMA everywhere (threshold 5.5e-3; measured absmax ~2e-3).
// R15: exact revert to R10 (best verified: 221.46us total, attn 115.4us).
//      R14's m==0 softmax triggered a spilling codegen config (345MB HBM
//      writes) despite identical VGPR count — the defer-max branch was
//      load-bearing for regalloc. R11/R12/R13 also neutral-to-negative.
//      This design family's empirical optimum:
//        - fp16 MFMA pipeline, Q pre-scaled by 0.125*log2(e)
//        - gemm_qkv 128x128 tile + fused V^T epilogue
//        - attn: 4 waves x 32q (2 groups sharing K/V frags), KVBLK=128,
//          global_load_lds staging, XCD-chunked swizzle, swapped QK^T,
//          C-operand -m bias + defer-max, per-lane l partials, setprio
//        - gemm_out 128x128 + bias

typedef _Float16 half8 __attribute__((ext_vector_type(8)));
typedef _Float16 half4 __attribute__((ext_vector_type(4)));
typedef __fp16 fp16x2 __attribute__((ext_vector_type(2)));  // native cvt_pkrtz type
typedef float floatx4 __attribute__((ext_vector_type(4)));

#define E 1024
#define NH 16
#define DH 64
#define SEQ 2048
#define BATCH 4

__device__ __forceinline__ void gload_lds16(const void* g, void* lds) {
  typedef __attribute__((address_space(1))) void gv;
  typedef __attribute__((address_space(3))) void lv;
  __builtin_amdgcn_global_load_lds((gv*)g, (lv*)lds, 16, 0, 0);
}

__device__ __forceinline__ float fast_exp2(float x) {
#if __has_builtin(__builtin_amdgcn_exp2f)
  return __builtin_amdgcn_exp2f(x);
#else
  return exp2f(x);
#endif
}

__device__ __forceinline__ float max3f(float a, float b, float c) {
  return fmaxf(fmaxf(a, b), c);  // clang fuses to v_max3_f32
}

// ---------------------------------------------------------------- convert (fused x, Wqkv, Wout)
__global__ __launch_bounds__(256)
void cvt3_f32_f16(const float* __restrict__ a, _Float16* __restrict__ oa, int na,
                  const float* __restrict__ b, _Float16* __restrict__ ob, int nb,
                  const float* __restrict__ c, _Float16* __restrict__ oc, int nc) {
  int i = blockIdx.x * 256 + threadIdx.x;
  const float* in;
  _Float16* out;
  int idx;
  if (i < na) { in = a; out = oa; idx = i; }
  else if (i < na + nb) { in = b; out = ob; idx = i - na; }
  else if (i < na + nb + nc) { in = c; out = oc; idx = i - na - nb; }
  else return;
  const float4* p = (const float4*)in;
  float4 u = p[2 * idx], v = p[2 * idx + 1];
  half8 h;
  h[0] = (_Float16)u.x; h[1] = (_Float16)u.y; h[2] = (_Float16)u.z; h[3] = (_Float16)u.w;
  h[4] = (_Float16)v.x; h[5] = (_Float16)v.y; h[6] = (_Float16)v.z; h[7] = (_Float16)v.w;
  ((half8*)out)[idx] = h;
}

// ---------------------------------------------------------------- QKV GEMM
// C[8192,3072] = A[8192,1024] * W[3072,1024]^T ; scatter into q/k (b,h,tok,d) and
// V^T (b,h,d,tok) fp16. Q pre-scaled by 1/sqrt(Dh)*log2(e) for exp2 softmax.
__global__ __launch_bounds__(256)
void gemm_qkv(const _Float16* __restrict__ A, const _Float16* __restrict__ W,
              _Float16* __restrict__ qo, _Float16* __restrict__ ko, _Float16* __restrict__ vt) {
  __shared__ __align__(16) _Float16 As[128 * 64];
  __shared__ __align__(16) _Float16 Bs[128 * 64];
  const int t = threadIdx.x;
  const int w = t >> 6, l = t & 63;
  const int wr = w >> 1, wc = w & 1;
  const int lr = l & 15, hi = l >> 4;
  const int tileRow = blockIdx.y * 128;
  const int tileCol = blockIdx.x * 128;
  const int ldsW = (t & ~63) * 16;
  floatx4 acc[4][4] = {};

  for (int k0 = 0; k0 < 1024; k0 += 64) {
    __syncthreads();
#pragma unroll
    for (int c = 0; c < 4; ++c) {
      int idx = c * 256 + t;
      int row = idx >> 3, g = idx & 7;
      gload_lds16(A + (size_t)(tileRow + row) * 1024 + k0 + g * 8, (char*)As + c * 4096 + ldsW);
      gload_lds16(W + (size_t)(tileCol + row) * 1024 + k0 + g * 8, (char*)Bs + c * 4096 + ldsW);
    }
    __syncthreads();
#pragma unroll
    for (int kk = 0; kk < 2; ++kk) {
      half8 af[4], bf[4];
#pragma unroll
      for (int m = 0; m < 4; ++m)
        af[m] = *(const half8*)(As + (wr * 64 + m * 16 + lr) * 64 + kk * 32 + hi * 8);
#pragma unroll
      for (int n = 0; n < 4; ++n)
        bf[n] = *(const half8*)(Bs + (wc * 64 + n * 16 + lr) * 64 + kk * 32 + hi * 8);
#pragma unroll
      for (int m = 0; m < 4; ++m)
#pragma unroll
        for (int n = 0; n < 4; ++n)
          acc[m][n] = __builtin_amdgcn_mfma_f32_16x16x32_f16(af[m], bf[n], acc[m][n], 0, 0, 0);
    }
  }
  // epilogue: C/D layout col=lane&15, row=(lane>>4)*4+j  [m89]
  const int sec = tileCol >> 10;  // 128-tile never straddles a 1024 section
  const int b = tileRow >> 11;
  const int tokBase = (tileRow & 2047) + wr * 64;
  if (sec == 2) {
    // V^T: vt[((b*NH+h)*DH + d)*SEQ + tok]; 4 consecutive tok per lane -> 8B stores
#pragma unroll
    for (int n = 0; n < 4; ++n) {
      int col = (tileCol & 1023) + wc * 64 + n * 16 + lr;
      int h = col >> 6, d = col & 63;
      _Float16* base = vt + (((size_t)b * NH + h) * DH + d) * SEQ + tokBase;
#pragma unroll
      for (int m = 0; m < 4; ++m) {
        half4 v;
#pragma unroll
        for (int j = 0; j < 4; ++j) v[j] = (_Float16)acc[m][n][j];
        *(half4*)(base + m * 16 + hi * 4) = v;
      }
    }
  } else {
    _Float16* dst = sec == 0 ? qo : ko;
    const float scaleq = sec == 0 ? 0.18033688011112042f : 1.0f;  // 0.125 * log2(e)
#pragma unroll
    for (int n = 0; n < 4; ++n) {
      int col = (tileCol & 1023) + wc * 64 + n * 16 + lr;
      int h = col >> 6, d = col & 63;
      _Float16* base = dst + (((size_t)b * NH + h) * SEQ + tokBase) * DH + d;
#pragma unroll
      for (int m = 0; m < 4; ++m)
#pragma unroll
        for (int j = 0; j < 4; ++j)
          base[(size_t)(m * 16 + hi * 4 + j) * DH] = (_Float16)(acc[m][n][j] * scaleq);
    }
  }
}

// ---------------------------------------------------------------- flash attention
// grid(1024 linear); XCD-chunked swizzle (FETCH 139->25MB measured).
// 4 waves x 32 q-rows (2 groups of 16); KV tile 128 = 2 sequential 64-key
// subtiles per barrier pair (16 drains instead of 32). global_load_lds staging.
// Swapped QK^T; -m in MFMA C-operand; defer-max; per-lane l partials.
__global__ __launch_bounds__(256, 3)
void attn(const _Float16* __restrict__ Q, const _Float16* __restrict__ Kg,
          const _Float16* __restrict__ VT, _Float16* __restrict__ O) {
  __shared__ __align__(16) _Float16 Ks[2][64 * 64];  // [sub][key][d] swizzled
  __shared__ __align__(16) _Float16 Vs[2][64 * 64];  // [sub][d][key] swizzled
  __shared__ __align__(16) _Float16 Ps[4][16 * 64];  // per-wave P [q][key], reused per group
  const int orig = blockIdx.x;
  const int nid = (orig & 7) * 128 + (orig >> 3);  // bijective: 1024 = 8 * 128
  const int qt = nid & 15, bh = nid >> 4;
  const int t = threadIdx.x, w = t >> 6, l = t & 63;
  const int lr = l & 15, hi = l >> 4;
  const int ldsW = (t & ~63) * 16;
  const _Float16* qb = Q + ((size_t)bh * SEQ + qt * 128 + w * 32) * DH;
  half8 qf[2][2];
#pragma unroll
  for (int g = 0; g < 2; ++g) {
    qf[g][0] = *(const half8*)(qb + (g * 16 + lr) * DH + hi * 8);
    qf[g][1] = *(const half8*)(qb + (g * 16 + lr) * DH + 32 + hi * 8);
  }
  floatx4 o0[4] = {}, o1[4] = {};
  float m0 = 0.f, m1 = 0.f, l0 = 0.f, l1 = 0.f;  // per-lane; l reduced in epilogue
  const _Float16* kb = Kg + (size_t)bh * SEQ * DH;
  const _Float16* vb = VT + (size_t)bh * DH * SEQ;
  char* pw = (char*)&Ps[w][0];
  const int lrm = lr & 7;
  uint32_t wra[4], rda[2];
#pragma unroll
  for (int n = 0; n < 4; ++n)
    wra[n] = lr * 128 + ((((2 * n + (hi >> 1)) ^ lrm)) << 4) + (hi & 1) * 8;
#pragma unroll
  for (int kk = 0; kk < 2; ++kk)
    rda[kk] = lr * 128 + (((4 * kk + hi) ^ lrm) << 4);

  // softmax for one group: biased scores s (already minus m), updates m/l/o, emits pk
  auto sm = [&](floatx4(&s)[4], float& mr, float& lsum, floatx4(&oa)[4], fp16x2(&pk)[4][2]) {
    float ma = max3f(s[0][0], s[0][1], s[0][2]);
    float mb = max3f(s[0][3], s[1][0], s[1][1]);
    float mc = max3f(s[1][2], s[1][3], s[2][0]);
    float md = max3f(s[2][1], s[2][2], s[2][3]);
    float me = max3f(s[3][0], s[3][1], s[3][2]);
    float mx = max3f(max3f(ma, mb, mc), fmaxf(md, me), s[3][3]);
    mx = fmaxf(mx, __shfl_xor(mx, 16));
    mx = fmaxf(mx, __shfl_xor(mx, 32));
    float rs = 0.f;
    if (__builtin_expect(__any(mx > 10.f), 0)) {
      float dm = fmaxf(mx, 0.f);
      float fac = fast_exp2(-dm);
      mr += dm;
      lsum *= fac;
#pragma unroll
      for (int j = 0; j < 4; ++j) {
        float fj = __shfl(fac, hi * 4 + j);  // row 4hi+j's factor lives at lane 4hi+j
#pragma unroll
        for (int n = 0; n < 4; ++n) oa[n][j] *= fj;
      }
#pragma unroll
      for (int n = 0; n < 4; ++n) {
        float p0 = fast_exp2(s[n][0] - dm), p1 = fast_exp2(s[n][1] - dm);
        float p2 = fast_exp2(s[n][2] - dm), p3 = fast_exp2(s[n][3] - dm);
        pk[n][0] = __builtin_amdgcn_cvt_pkrtz(p0, p1);
        pk[n][1] = __builtin_amdgcn_cvt_pkrtz(p2, p3);
        rs += p0 + p1 + p2 + p3;
      }
    } else {
#pragma unroll
      for (int n = 0; n < 4; ++n) {
        float p0 = fast_exp2(s[n][0]), p1 = fast_exp2(s[n][1]);
        float p2 = fast_exp2(s[n][2]), p3 = fast_exp2(s[n][3]);
        pk[n][0] = __builtin_amdgcn_cvt_pkrtz(p0, p1);
        pk[n][1] = __builtin_amdgcn_cvt_pkrtz(p2, p3);
        rs += p0 + p1 + p2 + p3;
      }
    }
    lsum += rs;
  };

  // P round-trip through per-wave LDS; emits the two A-frags for PV
  auto proute = [&](fp16x2(&pk)[4][2], half8(&pf)[2]) {
#pragma unroll
    for (int n = 0; n < 4; ++n) {
      uint2 v;
      v.x = __builtin_bit_cast(uint32_t, pk[n][0]);
      v.y = __builtin_bit_cast(uint32_t, pk[n][1]);
      *(uint2*)(pw + wra[n]) = v;
    }
    pf[0] = *(const half8*)(pw + rda[0]);
    pf[1] = *(const half8*)(pw + rda[1]);
  };

  for (int kt = 0; kt < SEQ / 128; ++kt) {
    __syncthreads();
    // stage 128 keys: K rows 0..127 -> Ks[0..1]; V (sub, d) -> Vs[0..1]
#pragma unroll
    for (int c = 0; c < 4; ++c) {
      int idx = c * 256 + t;
      int row = idx >> 3, g = idx & 7, gs = g ^ (row & 7);
      gload_lds16(kb + (size_t)(kt * 128 + row) * DH + gs * 8, (char*)Ks + c * 4096 + ldsW);
      int d = row & 63, sv = row >> 6;
      gload_lds16(vb + (size_t)d * SEQ + kt * 128 + sv * 64 + gs * 8,
                  (char*)Vs + c * 4096 + ldsW);
    }
    __syncthreads();
#pragma unroll
    for (int sb = 0; sb < 2; ++sb) {
      const char* Kbase = (const char*)Ks + sb * 8192;
      const char* Vbase = (const char*)Vs + sb * 8192;
      // K frags once, used by both q-groups
      half8 af[8];
#pragma unroll
      for (int kk = 0; kk < 2; ++kk) {
        int gl = kk * 4 + hi;
#pragma unroll
        for (int n = 0; n < 4; ++n) {
          int key = n * 16 + lr;
          af[kk * 4 + n] = *(const half8*)(Kbase + key * 128 + ((gl ^ (key & 7)) << 4));
        }
      }
      // --- group 0 QK^T
      floatx4 cb0 = {-m0, -m0, -m0, -m0};
      floatx4 s0[4] = {cb0, cb0, cb0, cb0};
      __builtin_amdgcn_s_setprio(1);
#pragma unroll
      for (int kk = 0; kk < 2; ++kk)
#pragma unroll
        for (int n = 0; n < 4; ++n)
          s0[n] = __builtin_amdgcn_mfma_f32_16x16x32_f16(af[kk * 4 + n], qf[0][kk], s0[n], 0, 0, 0);
      __builtin_amdgcn_s_setprio(0);
      // group 0 softmax + P route (s0 dies here)
      fp16x2 pk[4][2];
      half8 pf[2];
      sm(s0, m0, l0, o0, pk);
      proute(pk, pf);
      // --- group 1 QK^T (last use of af)
      floatx4 cb1 = {-m1, -m1, -m1, -m1};
      floatx4 s1[4] = {cb1, cb1, cb1, cb1};
      __builtin_amdgcn_s_setprio(1);
#pragma unroll
      for (int kk = 0; kk < 2; ++kk)
#pragma unroll
        for (int n = 0; n < 4; ++n)
          s1[n] = __builtin_amdgcn_mfma_f32_16x16x32_f16(af[kk * 4 + n], qf[1][kk], s1[n], 0, 0, 0);
      __builtin_amdgcn_s_setprio(0);
      // V frags once, used by both q-groups
      half8 vf[8];
#pragma unroll
      for (int kk = 0; kk < 2; ++kk) {
        int gl = kk * 4 + hi;
#pragma unroll
        for (int n = 0; n < 4; ++n) {
          int d = n * 16 + lr;
          vf[kk * 4 + n] = *(const half8*)(Vbase + d * 128 + ((gl ^ (d & 7)) << 4));
        }
      }
      // --- PV group 0
      __builtin_amdgcn_s_setprio(1);
#pragma unroll
      for (int kk = 0; kk < 2; ++kk)
#pragma unroll
        for (int n = 0; n < 4; ++n)
          o0[n] = __builtin_amdgcn_mfma_f32_16x16x32_f16(pf[kk], vf[kk * 4 + n], o0[n], 0, 0, 0);
      __builtin_amdgcn_s_setprio(0);
      // group 1 softmax + P route (Ps reused; same-wave DS ordering keeps it safe)
      sm(s1, m1, l1, o1, pk);
      proute(pk, pf);
      // --- PV group 1
      __builtin_amdgcn_s_setprio(1);
#pragma unroll
      for (int kk = 0; kk < 2; ++kk)
#pragma unroll
        for (int n = 0; n < 4; ++n)
          o1[n] = __builtin_amdgcn_mfma_f32_16x16x32_f16(pf[kk], vf[kk * 4 + n], o1[n], 0, 0, 0);
      __builtin_amdgcn_s_setprio(0);
    }
  }
  // epilogue: reduce l partials (4 lanes per q-row), normalize + store both groups
  l0 += __shfl_xor(l0, 16); l0 += __shfl_xor(l0, 32);
  l1 += __shfl_xor(l1, 16); l1 += __shfl_xor(l1, 32);
  const int b = bh >> 4, h = bh & 15;
#pragma unroll
  for (int g = 0; g < 2; ++g) {
    const floatx4* oa = g == 0 ? o0 : o1;
    float lg = g == 0 ? l0 : l1;
#pragma unroll
    for (int j = 0; j < 4; ++j) {
      float lj = __shfl(lg, hi * 4 + j);
      float inv = 1.f / lj;
      int tok = qt * 128 + w * 32 + g * 16 + hi * 4 + j;
      _Float16* ob = O + ((size_t)b * SEQ + tok) * E + h * DH;
#pragma unroll
      for (int n = 0; n < 4; ++n) ob[n * 16 + lr] = (_Float16)(oa[n][j] * inv);
    }
  }
}

// ---------------------------------------------------------------- out projection
__global__ __launch_bounds__(256)
void gemm_out(const _Float16* __restrict__ A, const _Float16* __restrict__ W,
              const float* __restrict__ bias, float* __restrict__ out) {
  __shared__ __align__(16) _Float16 As[128 * 64];
  __shared__ __align__(16) _Float16 Bs[128 * 64];
  const int t = threadIdx.x;
  const int w = t >> 6, l = t & 63;
  const int wr = w >> 1, wc = w & 1;
  const int lr = l & 15, hi = l >> 4;
  const int tileRow = blockIdx.y * 128;
  const int tileCol = blockIdx.x * 128;
  const int ldsW = (t & ~63) * 16;
  floatx4 acc[4][4] = {};

  for (int k0 = 0; k0 < 1024; k0 += 64) {
    __syncthreads();
#pragma unroll
    for (int c = 0; c < 4; ++c) {
      int idx = c * 256 + t;
      int row = idx >> 3, g = idx & 7;
      gload_lds16(A + (size_t)(tileRow + row) * 1024 + k0 + g * 8, (char*)As + c * 4096 + ldsW);
      gload_lds16(W + (size_t)(tileCol + row) * 1024 + k0 + g * 8, (char*)Bs + c * 4096 + ldsW);
    }
    __syncthreads();
#pragma unroll
    for (int kk = 0; kk < 2; ++kk) {
      half8 af[4], bf[4];
#pragma unroll
      for (int m = 0; m < 4; ++m)
        af[m] = *(const half8*)(As + (wr * 64 + m * 16 + lr) * 64 + kk * 32 + hi * 8);
#pragma unroll
      for (int n = 0; n < 4; ++n)
        bf[n] = *(const half8*)(Bs + (wc * 64 + n * 16 + lr) * 64 + kk * 32 + hi * 8);
#pragma unroll
      for (int m = 0; m < 4; ++m)
#pragma unroll
        for (int n = 0; n < 4; ++n)
          acc[m][n] = __builtin_amdgcn_mfma_f32_16x16x32_f16(af[m], bf[n], acc[m][n], 0, 0, 0);
    }
  }
#pragma unroll
  for (int n = 0; n < 4; ++n) {
    int col = tileCol + wc * 64 + n * 16 + lr;
    float bv = bias[col];
#pragma unroll
    for (int m = 0; m < 4; ++m) {
      int row = tileRow + wr * 64 + m * 16 + hi * 4;
#pragma unroll
      for (int j = 0; j < 4; ++j)
        out[(size_t)(row + j) * E + col] = acc[m][n][j] + bv;
    }
  }
}

// ---------------------------------------------------------------- launch
extern "C" void kernel_launch(void* const* d_in, const int* in_sizes, int n_in,
                              void* d_out, int out_size, void* d_ws, size_t ws_size,
                              hipStream_t stream) {
  const float* x = (const float*)d_in[0];
  const float* Wqkv = (const float*)d_in[1];
  const float* Wout = (const float*)d_in[2];
  const float* bout = (const float*)d_in[3];
  float* out = (float*)d_out;
  char* ws = (char*)d_ws;
  // workspace: [0,16M) x16 (later ao16) | [16,32) q16 | [32,48) k16 |
  //            [48,64) vt16 (V^T, written by gemm_qkv) | [64,70) wq16 | [70,72) wo16
  _Float16* x16 = (_Float16*)(ws);
  _Float16* q16 = (_Float16*)(ws + (16u << 20));
  _Float16* k16 = (_Float16*)(ws + (32u << 20));
  _Float16* vt16 = (_Float16*)(ws + (48u << 20));
  _Float16* wq16 = (_Float16*)(ws + (64u << 20));
  _Float16* wo16 = (_Float16*)(ws + (70u << 20));
  _Float16* ao16 = x16;  // x dead after gemm_qkv

  int n8x = in_sizes[0] / 8, n8q = in_sizes[1] / 8, n8o = in_sizes[2] / 8;
  int n8 = n8x + n8q + n8o;
  cvt3_f32_f16<<<(n8 + 255) / 256, 256, 0, stream>>>(x, x16, n8x, Wqkv, wq16, n8q, Wout, wo16, n8o);
  gemm_qkv<<<dim3(24, 64), 256, 0, stream>>>(x16, wq16, q16, k16, vt16);
  attn<<<dim3(1024), 256, 0, stream>>>(q16, k16, vt16, ao16);
  gemm_out<<<dim3(8, 64), 256, 0, stream>>>(ao16, wo16, bout, out);
}